// Round 1
// baseline (747.434 us; speedup 1.0000x reference)
//
#include <hip/hip_runtime.h>
#include <math.h>

#define NNODES 50000
#define NEDGE  800000
#define NG     3
#define D      128
#define GE     (NG*NEDGE)   // 2,400,000 combined edges

// ---------------------------------------------------------------------------
// K1: h = X @ W^T   (X [N,128] row-major, W [128,128] row-major [out][in])
// 64x64 tile per block, 256 threads, 4x4 register tile per thread.
// Both tiles staged TRANSPOSED in LDS (Xt[k][row], Wt[k][out]) so the inner
// loop is an outer product: 2x ds_read_b128 + 16 fma per k. Stride 64 is
// conflict-free for both staging writes (lane==row -> consecutive banks) and
// compute reads (ty*4 / tx*4 spread, 2-way max == free per m136).
// ---------------------------------------------------------------------------
__global__ __launch_bounds__(256) void k_gemm(const float* __restrict__ X,
                                              const float* __restrict__ W,
                                              float* __restrict__ h) {
    __shared__ float Xs[128 * 64];
    __shared__ float Ws[128 * 64];
    const int tid  = threadIdx.x;
    const int row0 = blockIdx.x * 64;
    const int col0 = blockIdx.y * 64;

    // ---- stage (transpose into LDS) ----
    const int rl = tid & 63;   // row/out within tile == lane
    const int kc = tid >> 6;   // 0..3 -> k range [kc*32, kc*32+32)
    int xr = row0 + rl; if (xr >= NNODES) xr = NNODES - 1;   // clamp (unused rows never stored)
    const float4* Xg = (const float4*)(X + (size_t)xr * D);
    const float4* Wg = (const float4*)(W + (size_t)(col0 + rl) * D);
#pragma unroll
    for (int it = 0; it < 8; ++it) {
        const int k4 = kc * 32 + it * 4;
        float4 xv = Xg[k4 >> 2];
        float4 wv = Wg[k4 >> 2];
        Xs[(k4 + 0) * 64 + rl] = xv.x;
        Xs[(k4 + 1) * 64 + rl] = xv.y;
        Xs[(k4 + 2) * 64 + rl] = xv.z;
        Xs[(k4 + 3) * 64 + rl] = xv.w;
        Ws[(k4 + 0) * 64 + rl] = wv.x;
        Ws[(k4 + 1) * 64 + rl] = wv.y;
        Ws[(k4 + 2) * 64 + rl] = wv.z;
        Ws[(k4 + 3) * 64 + rl] = wv.w;
    }
    __syncthreads();

    // ---- compute ----
    const int tx = tid & 15;   // out group  (4 outs)
    const int ty = tid >> 4;   // row group  (4 rows)
    float acc[4][4] = {};
    for (int k = 0; k < 128; ++k) {
        float4 xv4 = *(const float4*)&Xs[k * 64 + (ty << 2)];
        float4 wv4 = *(const float4*)&Ws[k * 64 + (tx << 2)];
        float xa[4] = {xv4.x, xv4.y, xv4.z, xv4.w};
        float wa[4] = {wv4.x, wv4.y, wv4.z, wv4.w};
#pragma unroll
        for (int i = 0; i < 4; ++i)
#pragma unroll
            for (int j = 0; j < 4; ++j)
                acc[i][j] += xa[i] * wa[j];
    }

    // ---- store ----
#pragma unroll
    for (int i = 0; i < 4; ++i) {
        const int r = row0 + (ty << 2) + i;
        if (r < NNODES) {
            float4 o = make_float4(acc[i][0], acc[i][1], acc[i][2], acc[i][3]);
            *(float4*)&h[(size_t)r * D + col0 + (tx << 2)] = o;
        }
    }
}

// ---------------------------------------------------------------------------
// K2: zero the per-row counts
// ---------------------------------------------------------------------------
__global__ void k_zero(int* __restrict__ count) {
    const int i = blockIdx.x * 256 + threadIdx.x;
    if (i < NNODES) count[i] = 0;
}

// ---------------------------------------------------------------------------
// K3: histogram of destination rows over the combined edge list
// ---------------------------------------------------------------------------
__global__ void k_hist(const int* __restrict__ rows, int* __restrict__ count) {
    const int i = blockIdx.x * 256 + threadIdx.x;
    if (i < GE) atomicAdd(&count[rows[i]], 1);
}

// ---------------------------------------------------------------------------
// K4: exclusive prefix scan over N counts (single block, 1024 threads,
// 49 elements serial per thread + Hillis-Steele block scan).
// Writes row_start[0..N] and an identical cursor[] for the scatter pass.
// ---------------------------------------------------------------------------
__global__ __launch_bounds__(1024) void k_scan(const int* __restrict__ count,
                                               int* __restrict__ row_start,
                                               int* __restrict__ cursor) {
    __shared__ int sums[1024];
    const int t = threadIdx.x;
    const int CH = (NNODES + 1023) / 1024;   // 49
    const int base = t * CH;
    int local = 0;
    for (int i = 0; i < CH; ++i) {
        const int idx = base + i;
        if (idx < NNODES) local += count[idx];
    }
    sums[t] = local;
    __syncthreads();
    for (int off = 1; off < 1024; off <<= 1) {
        int add = (t >= off) ? sums[t - off] : 0;
        __syncthreads();
        sums[t] += add;
        __syncthreads();
    }
    int running = sums[t] - local;   // exclusive prefix
    for (int i = 0; i < CH; ++i) {
        const int idx = base + i;
        if (idx < NNODES) {
            const int c = count[idx];
            row_start[idx] = running;
            cursor[idx]    = running;
            running += c;
        }
    }
    if (t == 0) row_start[NNODES] = GE;
}

// ---------------------------------------------------------------------------
// K5: scatter edges into CSR order; fold sigmoid(alpha_g) into the value.
// ---------------------------------------------------------------------------
__global__ void k_scatter(const int* __restrict__ rows, const int* __restrict__ cols,
                          const float* __restrict__ vals, const float* __restrict__ alpha,
                          int* __restrict__ cursor,
                          int* __restrict__ scol, float* __restrict__ sval) {
    const int i = blockIdx.x * 256 + threadIdx.x;
    if (i >= GE) return;
    const int g = i / NEDGE;                       // magic-mul div by constant
    const float gate = 1.0f / (1.0f + expf(-alpha[g]));
    const int r = rows[i];
    const int pos = atomicAdd(&cursor[r], 1);
    scol[pos] = cols[i];
    sval[pos] = gate * vals[i];
}

// ---------------------------------------------------------------------------
// K6: one wave per output row. Each lane owns 2 dims (float2). Per edge:
// broadcast (col,val), coalesced 512B read of h row, 2 fma. No atomics.
// ---------------------------------------------------------------------------
__global__ __launch_bounds__(256) void k_agg(const float* __restrict__ h,
                                             const int* __restrict__ row_start,
                                             const int* __restrict__ scol,
                                             const float* __restrict__ sval,
                                             float* __restrict__ out) {
    const int wid  = (blockIdx.x * 256 + threadIdx.x) >> 6;   // row
    const int lane = threadIdx.x & 63;
    if (wid >= NNODES) return;
    const int s = row_start[wid];
    const int e = row_start[wid + 1];
    const float2* __restrict__ h2 = (const float2*)h;
    float2 acc = make_float2(0.f, 0.f);
    for (int i = s; i < e; ++i) {
        const int   c = scol[i];
        const float v = sval[i];
        const float2 hv = h2[(size_t)c * 64 + lane];
        acc.x += v * hv.x;
        acc.y += v * hv.y;
    }
    ((float2*)out)[(size_t)wid * 64 + lane] = acc;
}

extern "C" void kernel_launch(void* const* d_in, const int* in_sizes, int n_in,
                              void* d_out, int out_size, void* d_ws, size_t ws_size,
                              hipStream_t stream) {
    const float* X     = (const float*)d_in[0];   // [N,128]
    const float* W     = (const float*)d_in[1];   // [128,128]
    const float* alpha = (const float*)d_in[2];   // [3,1]
    const int*   rows  = (const int*)d_in[3];     // [3,E] flat
    const int*   cols  = (const int*)d_in[4];
    const float* vals  = (const float*)d_in[5];
    float* out = (float*)d_out;

    // workspace layout (all 128B-aligned)
    char* ws = (char*)d_ws;
    float* h         = (float*)(ws + 0);           // 25,600,000 B
    int*   count     = (int*)  (ws + 25600000);    //    200,000 B
    int*   row_start = (int*)  (ws + 25800000);    //    200,004 B
    int*   cursor    = (int*)  (ws + 26000128);    //    200,000 B
    int*   scol      = (int*)  (ws + 26200128);    //  9,600,000 B
    float* sval      = (float*)(ws + 35800128);    //  9,600,000 B
    // total: 45,400,128 B

    hipLaunchKernelGGL(k_gemm, dim3((NNODES + 63) / 64, 2), dim3(256), 0, stream, X, W, h);
    hipLaunchKernelGGL(k_zero, dim3((NNODES + 255) / 256), dim3(256), 0, stream, count);
    hipLaunchKernelGGL(k_hist, dim3((GE + 255) / 256), dim3(256), 0, stream, rows, count);
    hipLaunchKernelGGL(k_scan, dim3(1), dim3(1024), 0, stream, count, row_start, cursor);
    hipLaunchKernelGGL(k_scatter, dim3((GE + 255) / 256), dim3(256), 0, stream,
                       rows, cols, vals, alpha, cursor, scol, sval);
    hipLaunchKernelGGL(k_agg, dim3((NNODES + 3) / 4), dim3(256), 0, stream,
                       h, row_start, scol, sval, out);
}

// Round 3
// 614.557 us; speedup vs baseline: 1.2162x; 1.2162x over previous
//
#include <hip/hip_runtime.h>
#include <math.h>

#define NNODES 50000
#define NEDGE  800000
#define NG     3
#define D      128
#define GE     (NG*NEDGE)   // 2,400,000 combined edges

// fp32 -> bf16 round-to-nearest-even (no NaN inputs here)
__device__ __forceinline__ unsigned short f2bf(float f) {
    unsigned u = __float_as_uint(f);
    return (unsigned short)((u + 0x7fffu + ((u >> 16) & 1u)) >> 16);
}

// ---------------------------------------------------------------------------
// K1: h = X @ W^T, stored as bf16 pairs [N, 64] uints. 64x64 tile, 256 thr.
// ---------------------------------------------------------------------------
__global__ __launch_bounds__(256) void k_gemm(const float* __restrict__ X,
                                              const float* __restrict__ W,
                                              unsigned* __restrict__ hbits) {
    __shared__ float Xs[128 * 64];
    __shared__ float Ws[128 * 64];
    const int tid  = threadIdx.x;
    const int row0 = blockIdx.x * 64;
    const int col0 = blockIdx.y * 64;

    const int rl = tid & 63;
    const int kc = tid >> 6;
    int xr = row0 + rl; if (xr >= NNODES) xr = NNODES - 1;
    const float4* Xg = (const float4*)(X + (size_t)xr * D);
    const float4* Wg = (const float4*)(W + (size_t)(col0 + rl) * D);
#pragma unroll
    for (int it = 0; it < 8; ++it) {
        const int k4 = kc * 32 + it * 4;
        float4 xv = Xg[k4 >> 2];
        float4 wv = Wg[k4 >> 2];
        Xs[(k4 + 0) * 64 + rl] = xv.x;
        Xs[(k4 + 1) * 64 + rl] = xv.y;
        Xs[(k4 + 2) * 64 + rl] = xv.z;
        Xs[(k4 + 3) * 64 + rl] = xv.w;
        Ws[(k4 + 0) * 64 + rl] = wv.x;
        Ws[(k4 + 1) * 64 + rl] = wv.y;
        Ws[(k4 + 2) * 64 + rl] = wv.z;
        Ws[(k4 + 3) * 64 + rl] = wv.w;
    }
    __syncthreads();

    const int tx = tid & 15;
    const int ty = tid >> 4;
    float acc[4][4] = {};
    for (int k = 0; k < 128; ++k) {
        float4 xv4 = *(const float4*)&Xs[k * 64 + (ty << 2)];
        float4 wv4 = *(const float4*)&Ws[k * 64 + (tx << 2)];
        float xa[4] = {xv4.x, xv4.y, xv4.z, xv4.w};
        float wa[4] = {wv4.x, wv4.y, wv4.z, wv4.w};
#pragma unroll
        for (int i = 0; i < 4; ++i)
#pragma unroll
            for (int j = 0; j < 4; ++j)
                acc[i][j] += xa[i] * wa[j];
    }

#pragma unroll
    for (int i = 0; i < 4; ++i) {
        const int r = row0 + (ty << 2) + i;
        if (r < NNODES) {
            uint2 o;
            o.x = (unsigned)f2bf(acc[i][0]) | ((unsigned)f2bf(acc[i][1]) << 16);
            o.y = (unsigned)f2bf(acc[i][2]) | ((unsigned)f2bf(acc[i][3]) << 16);
            *(uint2*)&hbits[(size_t)r * 64 + ((col0 + (tx << 2)) >> 1)] = o;
        }
    }
}

// ---------------------------------------------------------------------------
// K2: zero per-row counts
// ---------------------------------------------------------------------------
__global__ void k_zero(int* __restrict__ count) {
    const int i = blockIdx.x * 256 + threadIdx.x;
    if (i < NNODES) count[i] = 0;
}

// ---------------------------------------------------------------------------
// K3: histogram of destination rows
// ---------------------------------------------------------------------------
__global__ void k_hist(const int* __restrict__ rows, int* __restrict__ count) {
    const int i = blockIdx.x * 256 + threadIdx.x;
    if (i < GE) atomicAdd(&count[rows[i]], 1);
}

// ---------------------------------------------------------------------------
// K4: exclusive prefix scan over N counts — monolithic single-block version
// (identical structure to round-1's post-timing-clean kernel).
// ---------------------------------------------------------------------------
__global__ __launch_bounds__(1024) void k_scan(const int* __restrict__ count,
                                               int* __restrict__ row_start,
                                               int* __restrict__ cursor) {
    __shared__ int sums[1024];
    const int t = threadIdx.x;
    const int CH = (NNODES + 1023) / 1024;   // 49
    const int base = t * CH;
    int local = 0;
    for (int i = 0; i < CH; ++i) {
        const int idx = base + i;
        if (idx < NNODES) local += count[idx];
    }
    sums[t] = local;
    __syncthreads();
    for (int off = 1; off < 1024; off <<= 1) {
        int add = (t >= off) ? sums[t - off] : 0;
        __syncthreads();
        sums[t] += add;
        __syncthreads();
    }
    int running = sums[t] - local;   // exclusive prefix
    for (int i = 0; i < CH; ++i) {
        const int idx = base + i;
        if (idx < NNODES) {
            const int c = count[idx];
            row_start[idx] = running;
            cursor[idx]    = running;
            running += c;
        }
    }
    if (t == 0) row_start[NNODES] = GE;
}

// ---------------------------------------------------------------------------
// K5: scatter edges into CSR order (separate scol/sval arrays, round-1 style);
// fold sigmoid(alpha_g) into the value. Bounds-guarded.
// ---------------------------------------------------------------------------
__global__ void k_scatter(const int* __restrict__ rows, const int* __restrict__ cols,
                          const float* __restrict__ vals, const float* __restrict__ alpha,
                          int* __restrict__ cursor,
                          int* __restrict__ scol, float* __restrict__ sval) {
    const int i = blockIdx.x * 256 + threadIdx.x;
    if (i >= GE) return;
    const int g = i / NEDGE;
    const float gate = 1.0f / (1.0f + __expf(-alpha[g]));
    const int r = rows[i];
    const int pos = atomicAdd(&cursor[r], 1);
    if (pos >= 0 && pos < GE) {
        scol[pos] = cols[i];
        sval[pos] = gate * vals[i];
    }
}

// ---------------------------------------------------------------------------
// K6: one wave per output row; lane owns dims {2*lane, 2*lane+1} via one
// bf16-pair (4B) load per edge. Unrolled x8: 8 col loads + 8 val loads
// (broadcast), then 8 independent h gathers in flight, then FMAs.
// fp32 accumulate.
// ---------------------------------------------------------------------------
__global__ __launch_bounds__(256) void k_agg(const unsigned* __restrict__ hbits,
                                             const int* __restrict__ row_start,
                                             const int* __restrict__ scol,
                                             const float* __restrict__ sval,
                                             float* __restrict__ out) {
    const int wid  = (blockIdx.x * 256 + threadIdx.x) >> 6;
    const int lane = threadIdx.x & 63;
    if (wid >= NNODES) return;
    int s = row_start[wid];
    int e = row_start[wid + 1];
    // defensive clamps: never index outside the edge arrays
    if (s < 0) s = 0;
    if (e > GE) e = GE;
    float2 acc = make_float2(0.f, 0.f);

    int i = s;
    for (; i + 8 <= e; i += 8) {
        int   sc[8];
        float sv[8];
#pragma unroll
        for (int j = 0; j < 8; ++j) sc[j] = scol[i + j];
#pragma unroll
        for (int j = 0; j < 8; ++j) sv[j] = sval[i + j];
        unsigned hb[8];
#pragma unroll
        for (int j = 0; j < 8; ++j)
            hb[j] = hbits[(size_t)sc[j] * 64 + lane];
#pragma unroll
        for (int j = 0; j < 8; ++j) {
            const float lo = __uint_as_float(hb[j] << 16);
            const float hi = __uint_as_float(hb[j] & 0xffff0000u);
            acc.x += sv[j] * lo;
            acc.y += sv[j] * hi;
        }
    }
    for (; i < e; ++i) {
        const int   c = scol[i];
        const float v = sval[i];
        const unsigned hbv = hbits[(size_t)c * 64 + lane];
        acc.x += v * __uint_as_float(hbv << 16);
        acc.y += v * __uint_as_float(hbv & 0xffff0000u);
    }
    ((float2*)out)[(size_t)wid * 64 + lane] = acc;
}

extern "C" void kernel_launch(void* const* d_in, const int* in_sizes, int n_in,
                              void* d_out, int out_size, void* d_ws, size_t ws_size,
                              hipStream_t stream) {
    const float* X     = (const float*)d_in[0];
    const float* W     = (const float*)d_in[1];
    const float* alpha = (const float*)d_in[2];
    const int*   rows  = (const int*)d_in[3];
    const int*   cols  = (const int*)d_in[4];
    const float* vals  = (const float*)d_in[5];
    float* out = (float*)d_out;

    // workspace layout (all offsets 128B-aligned where it matters)
    char* ws = (char*)d_ws;
    unsigned* hbits   = (unsigned*)(ws + 0);          // 12,800,000 B
    int* count        = (int*)(ws + 12800000);        //    200,000 B
    int* row_start    = (int*)(ws + 13000000);        //    200,004 B (+pad)
    int* cursor       = (int*)(ws + 13200128);        //    200,000 B
    int* scol         = (int*)(ws + 13400128);        //  9,600,000 B
    float* sval       = (float*)(ws + 23000128);      //  9,600,000 B
    // total: 32,600,128 B

    hipLaunchKernelGGL(k_gemm, dim3((NNODES + 63) / 64, 2), dim3(256), 0, stream, X, W, hbits);
    hipLaunchKernelGGL(k_zero, dim3((NNODES + 255) / 256), dim3(256), 0, stream, count);
    hipLaunchKernelGGL(k_hist, dim3((GE + 255) / 256), dim3(256), 0, stream, rows, count);
    hipLaunchKernelGGL(k_scan, dim3(1), dim3(1024), 0, stream, count, row_start, cursor);
    hipLaunchKernelGGL(k_scatter, dim3((GE + 255) / 256), dim3(256), 0, stream,
                       rows, cols, vals, alpha, cursor, scol, sval);
    hipLaunchKernelGGL(k_agg, dim3((NNODES + 3) / 4), dim3(256), 0, stream,
                       hbits, row_start, scol, sval, out);
}